// Round 11
// baseline (457.125 us; speedup 1.0000x reference)
//
#include <hip/hip_runtime.h>

#define NN 50000
#define HH 8
#define ALPHA 0.2f
#define NPAD 50048   // NN rounded up to 128
#define NSPLIT 25024 // agg1 node split (multiple of 4)

typedef short short8 __attribute__((ext_vector_type(8)));
typedef float f32x4 __attribute__((ext_vector_type(4)));

__device__ __forceinline__ float elu_f(float x) {
  return x > 0.f ? x : __expf(x) - 1.f;
}

__device__ __forceinline__ unsigned short f2bf(float f) {
  unsigned int u = __float_as_uint(f);
  unsigned int r = (u + 0x7fffu + ((u >> 16) & 1u)) >> 16;
  return (unsigned short)r;
}

// ---------------- CSR build ----------------
__global__ void hist_kernel(const int* __restrict__ src, int* __restrict__ cnt, int E) {
  int e = blockIdx.x * blockDim.x + threadIdx.x;
  if (e < E) atomicAdd(&cnt[src[e]], 1);
}

__global__ __launch_bounds__(1024) void scan_blocks_kernel(const int* __restrict__ cnt,
    int* __restrict__ tmp, int* __restrict__ bsum, int n) {
  __shared__ int sh[1024];
  int i = blockIdx.x * 1024 + threadIdx.x;
  int v = (i < n) ? cnt[i] : 0;
  sh[threadIdx.x] = v;
  __syncthreads();
  for (int off = 1; off < 1024; off <<= 1) {
    int t = (threadIdx.x >= off) ? sh[threadIdx.x - off] : 0;
    __syncthreads();
    sh[threadIdx.x] += t;
    __syncthreads();
  }
  if (i < n) tmp[i] = sh[threadIdx.x] - v;
  if (threadIdx.x == 1023) bsum[blockIdx.x] = sh[1023];
}

// scan_top folded in: first wave sums bsum[0..blockIdx)
__global__ __launch_bounds__(1024) void scan_apply_kernel(const int* __restrict__ tmp,
    const int* __restrict__ bsum, int* __restrict__ row_ptr, int* __restrict__ nxt,
    int n, int E, int nb) {
  __shared__ int boff_sh;
  if (threadIdx.x < 64) {
    int L = threadIdx.x;
    int v = (L < nb && L < (int)blockIdx.x) ? bsum[L] : 0;
#pragma unroll
    for (int off = 1; off < 64; off <<= 1) v += __shfl_xor(v, off, 64);
    if (L == 0) boff_sh = v;
  }
  __syncthreads();
  int i = blockIdx.x * 1024 + threadIdx.x;
  if (i < n) {
    int s = tmp[i] + boff_sh;
    row_ptr[i] = s;
    nxt[i] = s;
  }
  if (i == 0) row_ptr[n] = E;
}

__global__ void scatter_kernel(const int* __restrict__ src, const int* __restrict__ dst,
                               int* __restrict__ nxt, int* __restrict__ col, int E) {
  int e = blockIdx.x * blockDim.x + threadIdx.x;
  if (e < E) {
    int p = atomicAdd(&nxt[src[e]], 1);
    col[p] = dst[e];
  }
}

// ---------------- layer-1 MFMA GEMM: x fp32 + W fp32 read directly (inline cvt) ----------------
// Cout node-major [N][512]; C-writes staged through LDS (Bs reused) for coalescing.
__global__ __launch_bounds__(256) void mfma_gemm1_kernel(
    const float* __restrict__ X, const float* __restrict__ W,
    const float* __restrict__ Aatt, unsigned short* __restrict__ Cout,
    float* __restrict__ ss, float* __restrict__ sd, int N) {
  __shared__ unsigned short Bs[64][264];    // also reused as 64x72 C-stage
  unsigned short* stage = &Bs[0][0];
  int w = threadIdx.x >> 6, L = threadIdx.x & 63;
  int quad = L >> 4, l16 = L & 15;
  int m0 = blockIdx.x * 64;
  int myrow = m0 + w * 16 + l16;
  int rowc = min(myrow, N - 1);          // clamp pad rows (results discarded)

  const float* Ar = X + (size_t)rowc * 256 + quad * 8;
  short8 areg[8];
#pragma unroll
  for (int ks = 0; ks < 8; ++ks) {
    float4 a0 = *(const float4*)(Ar + ks * 32);
    float4 a1 = *(const float4*)(Ar + ks * 32 + 4);
    areg[ks][0] = (short)f2bf(a0.x); areg[ks][1] = (short)f2bf(a0.y);
    areg[ks][2] = (short)f2bf(a0.z); areg[ks][3] = (short)f2bf(a0.w);
    areg[ks][4] = (short)f2bf(a1.x); areg[ks][5] = (short)f2bf(a1.y);
    areg[ks][6] = (short)f2bf(a1.z); areg[ks][7] = (short)f2bf(a1.w);
  }

  int tkp = threadIdx.x >> 6;            // k-pair base lane group
  int tc  = threadIdx.x & 63;

  for (int y = 0; y < HH; ++y) {
    __syncthreads();                     // previous head's stage copy done
    {
      // stage + transpose + convert: W[y] is [256][64] fp32 -> Bs[c][k] bf16
      const float* Bsrc = W + (size_t)y * 256 * 64;
#pragma unroll
      for (int i = 0; i < 32; ++i) {
        int kp = tkp + (i << 2);         // 0..127
        float w0 = Bsrc[(2 * kp) * 64 + tc];
        float w1 = Bsrc[(2 * kp + 1) * 64 + tc];
        unsigned dv = (unsigned)f2bf(w0) | ((unsigned)f2bf(w1) << 16);
        *(unsigned*)&Bs[tc][2 * kp] = dv;
      }
    }
    __syncthreads();

    f32x4 acc[4];
#pragma unroll
    for (int nt = 0; nt < 4; ++nt) acc[nt] = (f32x4)(0.f);
#pragma unroll
    for (int ks = 0; ks < 8; ++ks) {
#pragma unroll
      for (int nt = 0; nt < 4; ++nt) {
        short8 b = *(const short8*)&Bs[l16 + 16 * nt][ks * 32 + quad * 8];
        acc[nt] = __builtin_amdgcn_mfma_f32_16x16x32_bf16(areg[ks], b, acc[nt], 0, 0, 0);
      }
    }

    // scores from fp32 accumulators
    float as[4], ad[4];
#pragma unroll
    for (int nt = 0; nt < 4; ++nt) {
      as[nt] = Aatt[y * 128 + l16 + 16 * nt];
      ad[nt] = Aatt[y * 128 + 64 + l16 + 16 * nt];
    }
#pragma unroll
    for (int reg = 0; reg < 4; ++reg) {
      float p = 0.f, q = 0.f;
#pragma unroll
      for (int nt = 0; nt < 4; ++nt) {
        p += acc[nt][reg] * as[nt];
        q += acc[nt][reg] * ad[nt];
      }
#pragma unroll
      for (int off = 1; off < 16; off <<= 1) {
        p += __shfl_xor(p, off, 64);
        q += __shfl_xor(q, off, 64);
      }
      int row = m0 + w * 16 + quad * 4 + reg;
      if (l16 == 0 && row < N) {
        ss[(size_t)row * 8 + y] = p;
        sd[(size_t)row * 8 + y] = q;
      }
    }

    // stage C tile (64x64 bf16) into LDS (pitch 72), then coalesced copy out
    __syncthreads();                     // all Bs reads (MFMA) done
#pragma unroll
    for (int reg = 0; reg < 4; ++reg) {
      int lrow = w * 16 + quad * 4 + reg;
#pragma unroll
      for (int nt = 0; nt < 4; ++nt)
        stage[lrow * 72 + l16 + 16 * nt] = f2bf(acc[nt][reg]);
    }
    __syncthreads();
#pragma unroll
    for (int i = 0; i < 2; ++i) {
      int idx = threadIdx.x + 256 * i;   // 0..511
      int row = idx >> 3;
      int c8 = (idx & 7) << 3;
      if (m0 + row < N) {
        uint4 v = *(const uint4*)&stage[row * 72 + c8];
        *(uint4*)(Cout + ((size_t)(m0 + row)) * 512 + y * 64 + c8) = v;
      }
    }
  }
}

// ---------------- layer-2 MFMA GEMM (Wo fp32 staged w/ inline cvt), staged C-writes ----------------
__global__ __launch_bounds__(256) void mfma_gemm2_kernel(
    const unsigned short* __restrict__ A, const float* __restrict__ Wo,
    const float* __restrict__ Aatt, unsigned short* __restrict__ Cout,
    float* __restrict__ ss, float* __restrict__ sd, int N) {
  __shared__ unsigned short Bs[64][520];
  unsigned short* stage = &Bs[0][0];
  {
    int tkp = threadIdx.x >> 6;
    int tc  = threadIdx.x & 63;
#pragma unroll
    for (int i = 0; i < 64; ++i) {
      int kp = tkp + (i << 2);           // 0..255
      float w0 = Wo[(2 * kp) * 64 + tc];
      float w1 = Wo[(2 * kp + 1) * 64 + tc];
      unsigned dv = (unsigned)f2bf(w0) | ((unsigned)f2bf(w1) << 16);
      *(unsigned*)&Bs[tc][2 * kp] = dv;
    }
  }
  __syncthreads();

  int w = threadIdx.x >> 6, L = threadIdx.x & 63;
  int quad = L >> 4, l16 = L & 15;
  int m0 = blockIdx.x * 64;
  int myrow = m0 + w * 16 + l16;
  const unsigned short* Ar = A + (size_t)myrow * 512 + quad * 8;

  f32x4 acc[4];
#pragma unroll
  for (int nt = 0; nt < 4; ++nt) acc[nt] = (f32x4)(0.f);

  short8 a_cur = *(const short8*)(Ar);
  for (int k0 = 0; k0 < 512; k0 += 32) {
    short8 a_nxt;
    if (k0 + 32 < 512) a_nxt = *(const short8*)(Ar + k0 + 32);
#pragma unroll
    for (int nt = 0; nt < 4; ++nt) {
      short8 b = *(const short8*)&Bs[l16 + 16 * nt][k0 + quad * 8];
      acc[nt] = __builtin_amdgcn_mfma_f32_16x16x32_bf16(a_cur, b, acc[nt], 0, 0, 0);
    }
    a_cur = a_nxt;
  }

  float as[4], ad[4];
#pragma unroll
  for (int nt = 0; nt < 4; ++nt) {
    as[nt] = Aatt[l16 + 16 * nt];
    ad[nt] = Aatt[64 + l16 + 16 * nt];
  }
#pragma unroll
  for (int reg = 0; reg < 4; ++reg) {
    float p = 0.f, q = 0.f;
#pragma unroll
    for (int nt = 0; nt < 4; ++nt) {
      p += acc[nt][reg] * as[nt];
      q += acc[nt][reg] * ad[nt];
    }
#pragma unroll
    for (int off = 1; off < 16; off <<= 1) {
      p += __shfl_xor(p, off, 64);
      q += __shfl_xor(q, off, 64);
    }
    int row = m0 + w * 16 + quad * 4 + reg;
    if (l16 == 0 && row < N) { ss[row] = p; sd[row] = q; }
  }

  __syncthreads();                       // MFMA Bs reads done
#pragma unroll
  for (int reg = 0; reg < 4; ++reg) {
    int lrow = w * 16 + quad * 4 + reg;
#pragma unroll
    for (int nt = 0; nt < 4; ++nt)
      stage[lrow * 72 + l16 + 16 * nt] = f2bf(acc[nt][reg]);
  }
  __syncthreads();
#pragma unroll
  for (int i = 0; i < 2; ++i) {
    int idx = threadIdx.x + 256 * i;
    int row = idx >> 3;
    int c8 = (idx & 7) << 3;
    if (m0 + row < N) {
      uint4 v = *(const uint4*)&stage[row * 72 + c8];
      *(uint4*)(Cout + ((size_t)(m0 + row)) * 64 + c8) = v;
    }
  }
}

// ---------------- layer-1 aggregation: (node, feature-half) per wave; node-range split ----------------
__global__ __launch_bounds__(256) void agg1_kernel(const unsigned short* __restrict__ table,
    const float* __restrict__ ss, const float* __restrict__ sd,
    const int* __restrict__ row_ptr, const int* __restrict__ col,
    unsigned short* __restrict__ xc, int n0, int N) {
  int bid = blockIdx.x;
  int r8 = bid & 7;
  int p = r8 >> 2;                       // feature half (0: heads 0-3, 1: heads 4-7)
  int nb = ((bid >> 3) << 2) | (r8 & 3); // node-block index within this range
  int wid = threadIdx.x >> 6, L = threadIdx.x & 63;
  int n = n0 + nb * 4 + wid;
  if (n >= N) return;
  int hq = L >> 4;
  int h = p * 4 + hq;
  int el = L & 15;
  float ssn = ss[n * 8 + h];
  int k0 = row_ptr[n], deg = row_ptr[n + 1] - k0;
  float acc[4] = {0.f, 0.f, 0.f, 0.f};
  float rs = 0.f;
  const char* tb = (const char*)table + p * 512;

  for (int c0 = 0; c0 < deg; c0 += 64) {
    int j = c0 + L;
    int d_l = (j < deg) ? col[k0 + j] : 0;
    int m = min(64, deg - c0);
    for (int g = 0; g < m; g += 16) {
      int eoff = g + el;
      int de = __shfl(d_l, eoff, 64);
      float s = ssn + sd[(size_t)de * 8 + h];
      float e = __expf(-fmaxf(s, ALPHA * s));
      if (eoff >= m) e = 0.f;
      rs += e;
      int gm = min(16, m - g);
      uint2 rv[16];
#pragma unroll
      for (int t = 0; t < 16; ++t) {
        if (t < gm) {
          int dg = __builtin_amdgcn_readlane(d_l, g + t);
          rv[t] = *(const uint2*)(tb + (size_t)dg * 1024 + L * 8);
        }
      }
#pragma unroll
      for (int t = 0; t < 16; ++t) {
        if (t < gm) {
          float ew = __shfl(e, (hq << 4) + t, 64);
          acc[0] += ew * __uint_as_float(rv[t].x << 16);
          acc[1] += ew * __uint_as_float(rv[t].x & 0xffff0000u);
          acc[2] += ew * __uint_as_float(rv[t].y << 16);
          acc[3] += ew * __uint_as_float(rv[t].y & 0xffff0000u);
        }
      }
    }
  }
  rs += __shfl_xor(rs, 1, 64);
  rs += __shfl_xor(rs, 2, 64);
  rs += __shfl_xor(rs, 4, 64);
  rs += __shfl_xor(rs, 8, 64);
  float inv = 1.f / rs;
  ushort4 pk;
  pk.x = f2bf(elu_f(acc[0] * inv));
  pk.y = f2bf(elu_f(acc[1] * inv));
  pk.z = f2bf(elu_f(acc[2] * inv));
  pk.w = f2bf(elu_f(acc[3] * inv));
  *(ushort4*)(xc + (size_t)n * 512 + p * 256 + L * 4) = pk;
}

// ---------------- layer-2 aggregation + fused classifier ----------------
__global__ __launch_bounds__(256) void agg2_final_kernel(const unsigned short* __restrict__ table,
    const float* __restrict__ ss, const float* __restrict__ sd,
    const int* __restrict__ row_ptr, const int* __restrict__ col,
    const float* __restrict__ mlp_w, const float* __restrict__ mlp_b,
    float* __restrict__ out, int N) {
  __shared__ float wsh[40 * 65];
  __shared__ float bsh[40];
  __shared__ float osh[4][68];
  for (int i = threadIdx.x; i < 40 * 64; i += 256) wsh[(i >> 6) * 65 + (i & 63)] = mlp_w[i];
  if (threadIdx.x < 40) bsh[threadIdx.x] = mlp_b[threadIdx.x];
  __syncthreads();

  int wid = threadIdx.x >> 6, L = threadIdx.x & 63;
  int n = blockIdx.x * 4 + wid;
  bool act = (n < N);
  float o = 0.f;
  if (act) {
    float ssn = ss[n];
    int k0 = row_ptr[n], deg = row_ptr[n + 1] - k0;
    float acc = 0.f, rs = 0.f;
    const char* base = (const char*)table;
    for (int c0 = 0; c0 < deg; c0 += 64) {
      int j = c0 + L;
      int d_l = 0;
      float e_l = 0.f;
      if (j < deg) {
        d_l = col[k0 + j];
        float s = ssn + sd[d_l];
        e_l = __expf(-fmaxf(s, ALPHA * s));
      }
      rs += e_l;
      int m = min(64, deg - c0);
      int off_l = d_l << 7;
      for (int g = 0; g < m; g += 8) {
        int gm = min(8, m - g);
        unsigned hv[8];
#pragma unroll
        for (int t = 0; t < 8; ++t) {
          if (t < gm) {
            int so = __builtin_amdgcn_readlane(off_l, g + t);
            hv[t] = *(const unsigned short*)(base + so + L * 2);
          }
        }
#pragma unroll
        for (int t = 0; t < 8; ++t) {
          if (t < gm) {
            float ew = __uint_as_float(
                (unsigned)__builtin_amdgcn_readlane(__float_as_uint(e_l), g + t));
            acc += ew * __uint_as_float(hv[t] << 16);
          }
        }
      }
    }
#pragma unroll
    for (int off = 1; off < 64; off <<= 1) rs += __shfl_xor(rs, off, 64);
    o = elu_f(acc / rs);
  }
  osh[wid][L] = o;
  __syncthreads();
  if (act && L < 40) {
    const float* wr = wsh + L * 65;
    const float* orow = osh[wid];
    float acc = bsh[L];
#pragma unroll
    for (int j = 0; j < 64; ++j) acc += orow[j] * wr[j];
    out[(size_t)n * 40 + L] = acc;
  }
}

extern "C" void kernel_launch(void* const* d_in, const int* in_sizes, int n_in,
                              void* d_out, int out_size, void* d_ws, size_t ws_size,
                              hipStream_t stream) {
  (void)n_in; (void)out_size; (void)ws_size;
  const float* x  = (const float*)d_in[0];
  const int*   ei = (const int*)d_in[1];
  const float* W  = (const float*)d_in[2];
  const float* a  = (const float*)d_in[3];
  const float* Wo = (const float*)d_in[4];
  const float* ao = (const float*)d_in[5];
  const float* mw = (const float*)d_in[6];
  const float* mb = (const float*)d_in[7];
  float* out = (float*)d_out;

  const int N = NN;
  const int E = in_sizes[1] / 2;
  const int* src = ei;
  const int* dst = ei + E;

  char* ws = (char*)d_ws;
  size_t off = 0;
  auto alloc = [&](size_t bytes) {
    char* p = ws + off;
    off = (off + bytes + 255) & ~(size_t)255;
    return p;
  };
  unsigned short* h1b = (unsigned short*)alloc((size_t)N * 512 * 2);    // [N][512]
  float* ss1     = (float*)alloc((size_t)N * 8 * 4);
  float* sd1     = (float*)alloc((size_t)N * 8 * 4);
  unsigned short* xc = (unsigned short*)alloc((size_t)NPAD * 512 * 2);
  unsigned short* h2b = (unsigned short*)alloc((size_t)N * 64 * 2);
  float* ss2     = (float*)alloc((size_t)N * 4);
  float* sd2     = (float*)alloc((size_t)N * 4);
  int*   row_ptr = (int*)  alloc((size_t)(N + 1) * 4);
  int*   nxt     = (int*)  alloc((size_t)N * 4);
  int*   cnt     = (int*)  alloc((size_t)N * 4);
  int*   tmp     = (int*)  alloc((size_t)N * 4);
  int*   bsum    = (int*)  alloc(64 * 4);
  int*   colv    = (int*)  alloc((size_t)E * 4);

  int eb = (E + 255) / 256;
  int nb1024 = (N + 1023) / 1024;   // 49

  // CSR
  hipMemsetAsync(cnt, 0, (size_t)N * 4, stream);
  hipLaunchKernelGGL(hist_kernel, dim3(eb), dim3(256), 0, stream, src, cnt, E);
  hipLaunchKernelGGL(scan_blocks_kernel, dim3(nb1024), dim3(1024), 0, stream, cnt, tmp, bsum, N);
  hipLaunchKernelGGL(scan_apply_kernel, dim3(nb1024), dim3(1024), 0, stream,
                     tmp, bsum, row_ptr, nxt, N, E, nb1024);
  hipLaunchKernelGGL(scatter_kernel, dim3(eb), dim3(256), 0, stream, src, dst, nxt, colv, E);

  // layer 1
  hipLaunchKernelGGL(mfma_gemm1_kernel, dim3(NPAD / 64), dim3(256), 0, stream,
                     x, W, a, h1b, ss1, sd1, N);
  // agg1 split into two node ranges (tail diagnostic + same total work)
  hipLaunchKernelGGL(agg1_kernel, dim3(2 * (NSPLIT / 4)), dim3(256), 0, stream,
                     h1b, ss1, sd1, row_ptr, colv, xc, 0, NSPLIT);
  hipLaunchKernelGGL(agg1_kernel, dim3(2 * ((N - NSPLIT + 3) / 4)), dim3(256), 0, stream,
                     h1b, ss1, sd1, row_ptr, colv, xc, NSPLIT, N);

  // layer 2
  hipLaunchKernelGGL(mfma_gemm2_kernel, dim3(NPAD / 64), dim3(256), 0, stream,
                     xc, Wo, ao, h2b, ss2, sd2, N);
  hipLaunchKernelGGL(agg2_final_kernel, dim3((N + 3) / 4), dim3(256), 0, stream,
                     h2b, ss2, sd2, row_ptr, colv, mw, mb, out, N);
}

// Round 12
// 432.785 us; speedup vs baseline: 1.0562x; 1.0562x over previous
//
#include <hip/hip_runtime.h>

#define NN 50000
#define HH 8
#define ALPHA 0.2f
#define NPAD 50048   // NN rounded up to 128

typedef short short8 __attribute__((ext_vector_type(8)));
typedef float f32x4 __attribute__((ext_vector_type(4)));

__device__ __forceinline__ float elu_f(float x) {
  return x > 0.f ? x : __expf(x) - 1.f;
}

__device__ __forceinline__ unsigned short f2bf(float f) {
  unsigned int u = __float_as_uint(f);
  unsigned int r = (u + 0x7fffu + ((u >> 16) & 1u)) >> 16;
  return (unsigned short)r;
}

// ---------------- prep: xb bf16 [NPAD][256]; Wtc bf16 [512][256] (c-major, k-contig);
// Wot bf16 [64][512] ----------------
__global__ void cvt_all_kernel(const float* __restrict__ x, unsigned short* __restrict__ xb,
                               const float* __restrict__ W, unsigned short* __restrict__ Wtc,
                               const float* __restrict__ Wo, unsigned short* __restrict__ Wot,
                               int N) {
  int tid = blockIdx.x * 256 + threadIdx.x;
  int n4x = NPAD * 64;                       // float4 groups in xb
  if (tid < n4x) {
    int row = tid >> 6;
    ushort4 o;
    if (row < N) {
      float4 v = ((const float4*)x)[tid];
      o.x = f2bf(v.x); o.y = f2bf(v.y); o.z = f2bf(v.z); o.w = f2bf(v.w);
    } else {
      o.x = o.y = o.z = o.w = 0;
    }
    ((ushort4*)xb)[tid] = o;
    return;
  }
  int t1 = tid - n4x;
  if (t1 < 512 * 256) {                      // Wtc[c][k] <- W[h][k][cc], c=h*64+cc
    int c = t1 >> 8, k = t1 & 255;
    int h = c >> 6, cc = c & 63;
    Wtc[t1] = f2bf(W[((size_t)h * 256 + k) * 64 + cc]);
    return;
  }
  int t2 = t1 - 512 * 256;
  if (t2 < 64 * 512) {                       // Wot[c][k] <- Wo[k][c]
    int c = t2 >> 9, k = t2 & 511;
    Wot[t2] = f2bf(Wo[(size_t)k * 64 + c]);
  }
}

// ---------------- CSR build ----------------
__global__ void hist_kernel(const int* __restrict__ src, int* __restrict__ cnt, int E) {
  int e = blockIdx.x * blockDim.x + threadIdx.x;
  if (e < E) atomicAdd(&cnt[src[e]], 1);
}

__global__ __launch_bounds__(1024) void scan_blocks_kernel(const int* __restrict__ cnt,
    int* __restrict__ tmp, int* __restrict__ bsum, int n) {
  __shared__ int sh[1024];
  int i = blockIdx.x * 1024 + threadIdx.x;
  int v = (i < n) ? cnt[i] : 0;
  sh[threadIdx.x] = v;
  __syncthreads();
  for (int off = 1; off < 1024; off <<= 1) {
    int t = (threadIdx.x >= off) ? sh[threadIdx.x - off] : 0;
    __syncthreads();
    sh[threadIdx.x] += t;
    __syncthreads();
  }
  if (i < n) tmp[i] = sh[threadIdx.x] - v;
  if (threadIdx.x == 1023) bsum[blockIdx.x] = sh[1023];
}

__global__ __launch_bounds__(1024) void scan_apply_kernel(const int* __restrict__ tmp,
    const int* __restrict__ bsum, int* __restrict__ row_ptr, int* __restrict__ nxt,
    int n, int E, int nb) {
  __shared__ int boff_sh;
  if (threadIdx.x < 64) {
    int L = threadIdx.x;
    int v = (L < nb && L < (int)blockIdx.x) ? bsum[L] : 0;
#pragma unroll
    for (int off = 1; off < 64; off <<= 1) v += __shfl_xor(v, off, 64);
    if (L == 0) boff_sh = v;
  }
  __syncthreads();
  int i = blockIdx.x * 1024 + threadIdx.x;
  if (i < n) {
    int s = tmp[i] + boff_sh;
    row_ptr[i] = s;
    nxt[i] = s;
  }
  if (i == 0) row_ptr[n] = E;
}

__global__ void scatter_kernel(const int* __restrict__ src, const int* __restrict__ dst,
                               int* __restrict__ nxt, int* __restrict__ col, int E) {
  int e = blockIdx.x * blockDim.x + threadIdx.x;
  if (e < E) {
    int p = atomicAdd(&nxt[src[e]], 1);
    col[p] = dst[e];
  }
}

// ---------------- layer-1 single GEMM: C[N][512] = xb @ Wcat, 128x128 tiles ----------------
// grid (NPAD/128, 4). Wave w: wr=w>>1 row-half, wc=w&1 col-half; head y = blockIdx.y*2+wc.
__global__ __launch_bounds__(256) void mfma_gemm1_kernel(
    const unsigned short* __restrict__ A, const unsigned short* __restrict__ Wtc,
    const float* __restrict__ Aatt, unsigned short* __restrict__ Cout,
    float* __restrict__ ss, float* __restrict__ sd, int N) {
  __shared__ unsigned short As[128][40];   // 128 rows x 32 k, pitch 40
  __shared__ unsigned short Bs[128][40];   // 128 cols x 32 k
  int m0 = blockIdx.x * 128;
  int c0 = blockIdx.y * 128;
  int w = threadIdx.x >> 6, L = threadIdx.x & 63;
  int quad = L >> 4, l16 = L & 15;
  int wr = w >> 1, wc = w & 1;
  int y = blockIdx.y * 2 + wc;

  f32x4 acc[4][4];
#pragma unroll
  for (int mt = 0; mt < 4; ++mt)
#pragma unroll
    for (int nt = 0; nt < 4; ++nt) acc[mt][nt] = (f32x4)(0.f);

  // staging indices: thread t handles uint4 chunks idx = t, t+256 of each tile
  int sr0 = threadIdx.x >> 2;              // 0..63
  int sk0 = (threadIdx.x & 3) << 3;        // 0,8,16,24

  for (int k0 = 0; k0 < 256; k0 += 32) {
    __syncthreads();
    // A tile: rows m0..+128, k k0..+32
    *(uint4*)&As[sr0][sk0]      = *(const uint4*)(A + (size_t)(m0 + sr0) * 256 + k0 + sk0);
    *(uint4*)&As[sr0 + 64][sk0] = *(const uint4*)(A + (size_t)(m0 + sr0 + 64) * 256 + k0 + sk0);
    // B tile: cols c0..+128, k k0..+32
    *(uint4*)&Bs[sr0][sk0]      = *(const uint4*)(Wtc + (size_t)(c0 + sr0) * 256 + k0 + sk0);
    *(uint4*)&Bs[sr0 + 64][sk0] = *(const uint4*)(Wtc + (size_t)(c0 + sr0 + 64) * 256 + k0 + sk0);
    __syncthreads();

    short8 af[4], bf[4];
#pragma unroll
    for (int mt = 0; mt < 4; ++mt)
      af[mt] = *(const short8*)&As[wr * 64 + mt * 16 + l16][quad * 8];
#pragma unroll
    for (int nt = 0; nt < 4; ++nt)
      bf[nt] = *(const short8*)&Bs[wc * 64 + nt * 16 + l16][quad * 8];
#pragma unroll
    for (int mt = 0; mt < 4; ++mt)
#pragma unroll
      for (int nt = 0; nt < 4; ++nt)
        acc[mt][nt] = __builtin_amdgcn_mfma_f32_16x16x32_bf16(af[mt], bf[nt], acc[mt][nt], 0, 0, 0);
  }

  // epilogue: scores (head y, cols l16+16nt within head) + bf16 C
  float as[4], ad[4];
#pragma unroll
  for (int nt = 0; nt < 4; ++nt) {
    as[nt] = Aatt[y * 128 + l16 + 16 * nt];
    ad[nt] = Aatt[y * 128 + 64 + l16 + 16 * nt];
  }
#pragma unroll
  for (int mt = 0; mt < 4; ++mt) {
#pragma unroll
    for (int reg = 0; reg < 4; ++reg) {
      int row = m0 + wr * 64 + mt * 16 + quad * 4 + reg;
      float p = 0.f, q = 0.f;
#pragma unroll
      for (int nt = 0; nt < 4; ++nt) {
        p += acc[mt][nt][reg] * as[nt];
        q += acc[mt][nt][reg] * ad[nt];
      }
#pragma unroll
      for (int off = 1; off < 16; off <<= 1) {
        p += __shfl_xor(p, off, 64);
        q += __shfl_xor(q, off, 64);
      }
      if (l16 == 0 && row < N) {
        ss[(size_t)row * 8 + y] = p;
        sd[(size_t)row * 8 + y] = q;
      }
      if (row < N) {
#pragma unroll
        for (int nt = 0; nt < 4; ++nt)
          Cout[(size_t)row * 512 + y * 64 + l16 + 16 * nt] = f2bf(acc[mt][nt][reg]);
      }
    }
  }
}

// ---------------- layer-2 MFMA GEMM (Wot bf16, clean uint4 staging), staged C-writes ----------------
__global__ __launch_bounds__(256) void mfma_gemm2_kernel(
    const unsigned short* __restrict__ A, const unsigned short* __restrict__ Bt,
    const float* __restrict__ Aatt, unsigned short* __restrict__ Cout,
    float* __restrict__ ss, float* __restrict__ sd, int N) {
  __shared__ unsigned short Bs[64][520];
  unsigned short* stage = &Bs[0][0];
  {
    for (int c = threadIdx.x; c < 4096; c += 256) {
      int n = c >> 6;
      int kq = (c & 63) << 3;
      *(uint4*)&Bs[n][kq] = *(const uint4*)(Bt + (size_t)n * 512 + kq);
    }
  }
  __syncthreads();

  int w = threadIdx.x >> 6, L = threadIdx.x & 63;
  int quad = L >> 4, l16 = L & 15;
  int m0 = blockIdx.x * 64;
  int myrow = m0 + w * 16 + l16;
  const unsigned short* Ar = A + (size_t)myrow * 512 + quad * 8;

  f32x4 acc[4];
#pragma unroll
  for (int nt = 0; nt < 4; ++nt) acc[nt] = (f32x4)(0.f);

  short8 a_cur = *(const short8*)(Ar);
  for (int k0 = 0; k0 < 512; k0 += 32) {
    short8 a_nxt;
    if (k0 + 32 < 512) a_nxt = *(const short8*)(Ar + k0 + 32);
#pragma unroll
    for (int nt = 0; nt < 4; ++nt) {
      short8 b = *(const short8*)&Bs[l16 + 16 * nt][k0 + quad * 8];
      acc[nt] = __builtin_amdgcn_mfma_f32_16x16x32_bf16(a_cur, b, acc[nt], 0, 0, 0);
    }
    a_cur = a_nxt;
  }

  float as[4], ad[4];
#pragma unroll
  for (int nt = 0; nt < 4; ++nt) {
    as[nt] = Aatt[l16 + 16 * nt];
    ad[nt] = Aatt[64 + l16 + 16 * nt];
  }
#pragma unroll
  for (int reg = 0; reg < 4; ++reg) {
    float p = 0.f, q = 0.f;
#pragma unroll
    for (int nt = 0; nt < 4; ++nt) {
      p += acc[nt][reg] * as[nt];
      q += acc[nt][reg] * ad[nt];
    }
#pragma unroll
    for (int off = 1; off < 16; off <<= 1) {
      p += __shfl_xor(p, off, 64);
      q += __shfl_xor(q, off, 64);
    }
    int row = m0 + w * 16 + quad * 4 + reg;
    if (l16 == 0 && row < N) { ss[row] = p; sd[row] = q; }
  }

  __syncthreads();
#pragma unroll
  for (int reg = 0; reg < 4; ++reg) {
    int lrow = w * 16 + quad * 4 + reg;
#pragma unroll
    for (int nt = 0; nt < 4; ++nt)
      stage[lrow * 72 + l16 + 16 * nt] = f2bf(acc[nt][reg]);
  }
  __syncthreads();
#pragma unroll
  for (int i = 0; i < 2; ++i) {
    int idx = threadIdx.x + 256 * i;
    int row = idx >> 3;
    int c8 = (idx & 7) << 3;
    if (m0 + row < N) {
      uint4 v = *(const uint4*)&stage[row * 72 + c8];
      *(uint4*)(Cout + ((size_t)(m0 + row)) * 64 + c8) = v;
    }
  }
}

// ---------------- layer-1 aggregation: (node, feature-half) per wave ----------------
__global__ __launch_bounds__(256) void agg1_kernel(const unsigned short* __restrict__ table,
    const float* __restrict__ ss, const float* __restrict__ sd,
    const int* __restrict__ row_ptr, const int* __restrict__ col,
    unsigned short* __restrict__ xc, int N) {
  int bid = blockIdx.x;
  int r8 = bid & 7;
  int p = r8 >> 2;
  int nb = ((bid >> 3) << 2) | (r8 & 3);
  int wid = threadIdx.x >> 6, L = threadIdx.x & 63;
  int n = nb * 4 + wid;
  if (n >= N) return;
  int hq = L >> 4;
  int h = p * 4 + hq;
  int el = L & 15;
  float ssn = ss[n * 8 + h];
  int k0 = row_ptr[n], deg = row_ptr[n + 1] - k0;
  float acc[4] = {0.f, 0.f, 0.f, 0.f};
  float rs = 0.f;
  const char* tb = (const char*)table + p * 512;

  for (int c0 = 0; c0 < deg; c0 += 64) {
    int j = c0 + L;
    int d_l = (j < deg) ? col[k0 + j] : 0;
    int m = min(64, deg - c0);
    for (int g = 0; g < m; g += 16) {
      int eoff = g + el;
      int de = __shfl(d_l, eoff, 64);
      float s = ssn + sd[(size_t)de * 8 + h];
      float e = __expf(-fmaxf(s, ALPHA * s));
      if (eoff >= m) e = 0.f;
      rs += e;
      int gm = min(16, m - g);
      uint2 rv[16];
#pragma unroll
      for (int t = 0; t < 16; ++t) {
        if (t < gm) {
          int dg = __builtin_amdgcn_readlane(d_l, g + t);
          rv[t] = *(const uint2*)(tb + (size_t)dg * 1024 + L * 8);
        }
      }
#pragma unroll
      for (int t = 0; t < 16; ++t) {
        if (t < gm) {
          float ew = __shfl(e, (hq << 4) + t, 64);
          acc[0] += ew * __uint_as_float(rv[t].x << 16);
          acc[1] += ew * __uint_as_float(rv[t].x & 0xffff0000u);
          acc[2] += ew * __uint_as_float(rv[t].y << 16);
          acc[3] += ew * __uint_as_float(rv[t].y & 0xffff0000u);
        }
      }
    }
  }
  rs += __shfl_xor(rs, 1, 64);
  rs += __shfl_xor(rs, 2, 64);
  rs += __shfl_xor(rs, 4, 64);
  rs += __shfl_xor(rs, 8, 64);
  float inv = 1.f / rs;
  ushort4 pk;
  pk.x = f2bf(elu_f(acc[0] * inv));
  pk.y = f2bf(elu_f(acc[1] * inv));
  pk.z = f2bf(elu_f(acc[2] * inv));
  pk.w = f2bf(elu_f(acc[3] * inv));
  *(ushort4*)(xc + (size_t)n * 512 + p * 256 + L * 4) = pk;
}

// ---------------- layer-2 aggregation + fused classifier ----------------
__global__ __launch_bounds__(256) void agg2_final_kernel(const unsigned short* __restrict__ table,
    const float* __restrict__ ss, const float* __restrict__ sd,
    const int* __restrict__ row_ptr, const int* __restrict__ col,
    const float* __restrict__ mlp_w, const float* __restrict__ mlp_b,
    float* __restrict__ out, int N) {
  __shared__ float wsh[40 * 65];
  __shared__ float bsh[40];
  __shared__ float osh[4][68];
  for (int i = threadIdx.x; i < 40 * 64; i += 256) wsh[(i >> 6) * 65 + (i & 63)] = mlp_w[i];
  if (threadIdx.x < 40) bsh[threadIdx.x] = mlp_b[threadIdx.x];
  __syncthreads();

  int wid = threadIdx.x >> 6, L = threadIdx.x & 63;
  int n = blockIdx.x * 4 + wid;
  bool act = (n < N);
  float o = 0.f;
  if (act) {
    float ssn = ss[n];
    int k0 = row_ptr[n], deg = row_ptr[n + 1] - k0;
    float acc = 0.f, rs = 0.f;
    const char* base = (const char*)table;
    for (int c0 = 0; c0 < deg; c0 += 64) {
      int j = c0 + L;
      int d_l = 0;
      float e_l = 0.f;
      if (j < deg) {
        d_l = col[k0 + j];
        float s = ssn + sd[d_l];
        e_l = __expf(-fmaxf(s, ALPHA * s));
      }
      rs += e_l;
      int m = min(64, deg - c0);
      int off_l = d_l << 7;
      for (int g = 0; g < m; g += 8) {
        int gm = min(8, m - g);
        unsigned hv[8];
#pragma unroll
        for (int t = 0; t < 8; ++t) {
          if (t < gm) {
            int so = __builtin_amdgcn_readlane(off_l, g + t);
            hv[t] = *(const unsigned short*)(base + so + L * 2);
          }
        }
#pragma unroll
        for (int t = 0; t < 8; ++t) {
          if (t < gm) {
            float ew = __uint_as_float(
                (unsigned)__builtin_amdgcn_readlane(__float_as_uint(e_l), g + t));
            acc += ew * __uint_as_float(hv[t] << 16);
          }
        }
      }
    }
#pragma unroll
    for (int off = 1; off < 64; off <<= 1) rs += __shfl_xor(rs, off, 64);
    o = elu_f(acc / rs);
  }
  osh[wid][L] = o;
  __syncthreads();
  if (act && L < 40) {
    const float* wr = wsh + L * 65;
    const float* orow = osh[wid];
    float acc = bsh[L];
#pragma unroll
    for (int j = 0; j < 64; ++j) acc += orow[j] * wr[j];
    out[(size_t)n * 40 + L] = acc;
  }
}

extern "C" void kernel_launch(void* const* d_in, const int* in_sizes, int n_in,
                              void* d_out, int out_size, void* d_ws, size_t ws_size,
                              hipStream_t stream) {
  (void)n_in; (void)out_size; (void)ws_size;
  const float* x  = (const float*)d_in[0];
  const int*   ei = (const int*)d_in[1];
  const float* W  = (const float*)d_in[2];
  const float* a  = (const float*)d_in[3];
  const float* Wo = (const float*)d_in[4];
  const float* ao = (const float*)d_in[5];
  const float* mw = (const float*)d_in[6];
  const float* mb = (const float*)d_in[7];
  float* out = (float*)d_out;

  const int N = NN;
  const int E = in_sizes[1] / 2;
  const int* src = ei;
  const int* dst = ei + E;

  char* ws = (char*)d_ws;
  size_t off = 0;
  auto alloc = [&](size_t bytes) {
    char* p = ws + off;
    off = (off + bytes + 255) & ~(size_t)255;
    return p;
  };
  unsigned short* xb  = (unsigned short*)alloc((size_t)NPAD * 256 * 2);   // 25.6 MB
  unsigned short* Wtc = (unsigned short*)alloc((size_t)512 * 256 * 2);
  unsigned short* Wot = (unsigned short*)alloc((size_t)64 * 512 * 2);
  unsigned short* h1b = (unsigned short*)alloc((size_t)N * 512 * 2);      // [N][512]
  float* ss1     = (float*)alloc((size_t)N * 8 * 4);
  float* sd1     = (float*)alloc((size_t)N * 8 * 4);
  unsigned short* xc = (unsigned short*)alloc((size_t)NPAD * 512 * 2);
  unsigned short* h2b = (unsigned short*)alloc((size_t)N * 64 * 2);
  float* ss2     = (float*)alloc((size_t)N * 4);
  float* sd2     = (float*)alloc((size_t)N * 4);
  int*   row_ptr = (int*)  alloc((size_t)(N + 1) * 4);
  int*   nxt     = (int*)  alloc((size_t)N * 4);
  int*   cnt     = (int*)  alloc((size_t)N * 4);
  int*   tmp     = (int*)  alloc((size_t)N * 4);
  int*   bsum    = (int*)  alloc(64 * 4);
  int*   colv    = (int*)  alloc((size_t)E * 4);

  int eb = (E + 255) / 256;
  int nb1024 = (N + 1023) / 1024;   // 49
  int cvt_total = NPAD * 64 + 512 * 256 + 64 * 512;

  // prep
  hipLaunchKernelGGL(cvt_all_kernel, dim3((cvt_total + 255) / 256), dim3(256), 0, stream,
                     x, xb, W, Wtc, Wo, Wot, N);

  // CSR
  hipMemsetAsync(cnt, 0, (size_t)N * 4, stream);
  hipLaunchKernelGGL(hist_kernel, dim3(eb), dim3(256), 0, stream, src, cnt, E);
  hipLaunchKernelGGL(scan_blocks_kernel, dim3(nb1024), dim3(1024), 0, stream, cnt, tmp, bsum, N);
  hipLaunchKernelGGL(scan_apply_kernel, dim3(nb1024), dim3(1024), 0, stream,
                     tmp, bsum, row_ptr, nxt, N, E, nb1024);
  hipLaunchKernelGGL(scatter_kernel, dim3(eb), dim3(256), 0, stream, src, dst, nxt, colv, E);

  // layer 1: single 128x128-tile GEMM over all heads
  hipLaunchKernelGGL(mfma_gemm1_kernel, dim3(NPAD / 128, 4), dim3(256), 0, stream,
                     xb, Wtc, a, h1b, ss1, sd1, N);
  hipLaunchKernelGGL(agg1_kernel, dim3(2 * ((N + 3) / 4)), dim3(256), 0, stream,
                     h1b, ss1, sd1, row_ptr, colv, xc, N);

  // layer 2
  hipLaunchKernelGGL(mfma_gemm2_kernel, dim3(NPAD / 64), dim3(256), 0, stream,
                     xc, Wot, ao, h2b, ss2, sd2, N);
  hipLaunchKernelGGL(agg2_final_kernel, dim3((N + 3) / 4), dim3(256), 0, stream,
                     h2b, ss2, sd2, row_ptr, colv, mw, mb, out, N);
}